// Round 8
// baseline (1880.645 us; speedup 1.0000x reference)
//
#include <hip/hip_runtime.h>
#include <hip/hip_bf16.h>
#include <math.h>

// TrueHopfieldLayer: HIDDEN=512, B=4, S=2048, 5 iters, thresh 1e-4.
// Round 14: r13 DMA staging + PROPER counted-vmcnt pipeline (T4).
// r13 post-mortem: DMA staging was clean (conflicts halved, no spill) but
// SBAR drained vmcnt(0) every phase with distance-1 issue -> exposed DMA
// latency 8x/kt (245us vs r10's 218). Fix (single change):
//  - 3-buffer rotation UB[3][16384]; phase p uses buf p%3.
//  - every phase issues its DMA TWO phases ahead into buf (p+2)%3 (freed
//    two phases ago; readers' lgkm drained before the prior barrier).
//  - phase barrier = s_waitcnt vmcnt(4) lgkmcnt(0); s_barrier -- waits only
//    this phase's 4 DMAs; the next phase's 4 stay in flight across the
//    barrier and across softmax (FBARs stay lgkm-only).
//  - uniform issue: last-kt phases wrap to kt=0 (harmless overfetch) so
//    vmcnt(4) is exact everywhere. Prologue DMAs issued AFTER the Q block
//    so compiler Q-load waits drain before counting starts.
// Everything else byte-identical to r13. LDS ~148KB.
#define HH 512
#define BB 4
#define SS 2048
#define NN (BB*SS)
#define SCALE_F 0.04419417382415922f     // 1/sqrt(512)
#define THRESH 1e-4f
#define CTL_FLOATS 1024

typedef __attribute__((ext_vector_type(8))) short bf16x8;
typedef __attribute__((ext_vector_type(4))) float f32x4;

struct Ctl { float sum_d; float sum_o; int iters; int conv; int cur; int bf[10]; };

__device__ __forceinline__ float b2f(unsigned short u) {
    union { unsigned int i; float f; } c; c.i = ((unsigned int)u) << 16; return c.f;
}
__device__ __forceinline__ unsigned short f2b(float f) {
    unsigned int x = __float_as_uint(f);
    unsigned int r = (x + 0x7FFFu + ((x >> 16) & 1u)) >> 16;   // RNE
    return (unsigned short)r;
}
__device__ __forceinline__ void splitf(float x, unsigned short& h, unsigned short& l) {
    h = f2b(x);
    l = f2b(x - b2f(h));
}
__device__ __forceinline__ f32x4 MF(bf16x8 a, bf16x8 b, f32x4 c) {
    return __builtin_amdgcn_mfma_f32_16x16x32_bf16(a, b, c, 0, 0, 0);
}

typedef __attribute__((address_space(1))) const unsigned int gu32;
typedef __attribute__((address_space(3))) unsigned int lu32;
// 16B/lane direct global->LDS DMA. LDS dest is wave-uniform base; HW adds lane*16.
__device__ __forceinline__ void gl_lds16(const unsigned short* g, unsigned short* l) {
    __builtin_amdgcn_global_load_lds((gu32*)g, (lu32*)l, 16, 0, 0);
}

// counted phase barrier: wait for the 4 oldest DMAs (this phase's), keep the
// 4 newer in flight across the barrier. lgkm(0) drains prior phase ds reads.
#define WBAR() do { \
    asm volatile("s_waitcnt vmcnt(4) lgkmcnt(0)" ::: "memory"); \
    __builtin_amdgcn_s_barrier(); \
    asm volatile("" ::: "memory"); \
} while (0)
// softmax barrier: LDS-only drain; in-flight DMA (vmcnt) preserved
#define FBAR() do { \
    asm volatile("s_waitcnt lgkmcnt(0)" ::: "memory"); \
    __builtin_amdgcn_s_barrier(); \
    asm volatile("" ::: "memory"); \
} while (0)

// ---------- dtype detection (proven) ----------
__global__ __launch_bounds__(256) void detect_dtypes(
        const void* p0, const void* p1, const void* p2, const void* p3, const void* p4,
        const void* p5, const void* p6, const void* p7, const void* p8, Ctl* sc)
{
    const void* ps[9] = {p0,p1,p2,p3,p4,p5,p6,p7,p8};
    const int   ns[9] = {NN*HH, HH*HH, HH, HH*HH, HH, HH*HH, HH, HH*HH, HH};
    const int i = blockIdx.x;
    const unsigned short* u = (const unsigned short*)ps[i];
    const int n = ns[i] < 4096 ? ns[i] : 4096;
    __shared__ int cnt;
    if (threadIdx.x == 0) cnt = 0;
    __syncthreads();
    int c = 0;
    for (int j = threadIdx.x; j < n; j += 256) {
        const int e = (u[j] >> 7) & 0xFF;
        if (e < 32 || e >= 224) ++c;
    }
    if (c) atomicAdd(&cnt, c);
    __syncthreads();
    if (threadIdx.x == 0) sc->bf[i] = (cnt * 16 < n) ? 1 : 0;
}

__global__ __launch_bounds__(64) void init_flags(Ctl* sc) {
    if (threadIdx.x == 0) {
        sc->iters = 0; sc->conv = 0; sc->cur = 0; sc->sum_d = 0.f; sc->sum_o = 0.f;
        int any = 0;
        for (int i = 0; i < 9; ++i) any |= sc->bf[i];
        sc->bf[9] = any;
    }
}

// ---------- MFMA GEMM: C = X @ W^T + bias ----------
// mode 0: fp32 out (Q->state). mode 1: external out (X = state[cur] fp32 when xIdx==-2).
// mode 3: K -> KH,KL row-major + KTH,KTL transposed ([b][h][s]) planes.
// mode 4: V -> transposed planes into dead state buffer buf[1^cur].
__global__ __launch_bounds__(256) void mfma_gemm(
    const void* __restrict__ Xv, int xIdx,
    const void* __restrict__ Wv, int wIdx,
    const void* __restrict__ Bv, int bIdx,
    float* __restrict__ outF, void* __restrict__ outExt,
    unsigned short* __restrict__ pKH, unsigned short* __restrict__ pKL,
    unsigned short* __restrict__ pKTH, unsigned short* __restrict__ pKTL,
    float* __restrict__ S0w, float* __restrict__ S1w,
    int mode, const Ctl* __restrict__ sc)
{
    __shared__ unsigned short Xh[64][72], Xl[64][72], Wh[64][72], Wl[64][72];
    const int tid = threadIdx.x;
    const int cur = sc->cur;
    const void* Xp = (xIdx == -2) ? (const void*)(cur ? S1w : S0w) : Xv;
    const bool xbf = (xIdx >= 0) && (sc->bf[xIdx] != 0);
    const bool wbf = (sc->bf[wIdx] != 0);
    const bool bbf = (sc->bf[bIdx] != 0);
    const bool obf = (mode == 1) && (sc->bf[9] != 0);
    const bool xs = !xbf, ws = !wbf;

    const int m0 = blockIdx.x * 64, n0 = blockIdx.y * 64;
    const int lane = tid & 63, w = tid >> 6;
    const int mi = w & 1, ni = w >> 1;
    const int quad = lane >> 4, l16 = lane & 15;
    const int srow = tid >> 2, skb = (tid & 3) * 16;

    f32x4 acc[2][2];
    #pragma unroll
    for (int a = 0; a < 2; ++a)
        #pragma unroll
        for (int bq = 0; bq < 2; ++bq) acc[a][bq] = (f32x4){0.f, 0.f, 0.f, 0.f};

    for (int kc = 0; kc < HH; kc += 64) {
        __syncthreads();
        {
            float v[16];
            if (xbf) {
                const unsigned short* p = (const unsigned short*)Xp + (size_t)(m0 + srow)*HH + kc + skb;
                #pragma unroll
                for (int i = 0; i < 4; ++i) {
                    ushort4 t = *(const ushort4*)(p + 4*i);
                    v[4*i]=b2f(t.x); v[4*i+1]=b2f(t.y); v[4*i+2]=b2f(t.z); v[4*i+3]=b2f(t.w);
                }
            } else {
                const float* p = (const float*)Xp + (size_t)(m0 + srow)*HH + kc + skb;
                #pragma unroll
                for (int i = 0; i < 4; ++i) {
                    float4 t = *(const float4*)(p + 4*i);
                    v[4*i]=t.x; v[4*i+1]=t.y; v[4*i+2]=t.z; v[4*i+3]=t.w;
                }
            }
            #pragma unroll
            for (int i = 0; i < 4; ++i) {
                unsigned short h[4], l[4];
                #pragma unroll
                for (int j = 0; j < 4; ++j) splitf(v[4*i+j], h[j], l[j]);
                *(ushort4*)&Xh[srow][skb + 4*i] = make_ushort4(h[0], h[1], h[2], h[3]);
                if (xs) *(ushort4*)&Xl[srow][skb + 4*i] = make_ushort4(l[0], l[1], l[2], l[3]);
            }
        }
        {
            float v[16];
            if (wbf) {
                const unsigned short* p = (const unsigned short*)Wv + (size_t)(n0 + srow)*HH + kc + skb;
                #pragma unroll
                for (int i = 0; i < 4; ++i) {
                    ushort4 t = *(const ushort4*)(p + 4*i);
                    v[4*i]=b2f(t.x); v[4*i+1]=b2f(t.y); v[4*i+2]=b2f(t.z); v[4*i+3]=b2f(t.w);
                }
            } else {
                const float* p = (const float*)Wv + (size_t)(n0 + srow)*HH + kc + skb;
                #pragma unroll
                for (int i = 0; i < 4; ++i) {
                    float4 t = *(const float4*)(p + 4*i);
                    v[4*i]=t.x; v[4*i+1]=t.y; v[4*i+2]=t.z; v[4*i+3]=t.w;
                }
            }
            #pragma unroll
            for (int i = 0; i < 4; ++i) {
                unsigned short h[4], l[4];
                #pragma unroll
                for (int j = 0; j < 4; ++j) splitf(v[4*i+j], h[j], l[j]);
                *(ushort4*)&Wh[srow][skb + 4*i] = make_ushort4(h[0], h[1], h[2], h[3]);
                if (ws) *(ushort4*)&Wl[srow][skb + 4*i] = make_ushort4(l[0], l[1], l[2], l[3]);
            }
        }
        __syncthreads();
        #pragma unroll
        for (int d = 0; d < 2; ++d) {
            const int kl = 32*d + quad*8;
            #pragma unroll
            for (int mt = 0; mt < 2; ++mt) {
                const int xr = 32*mi + 16*mt + l16;
                bf16x8 ahx = *(const bf16x8*)&Xh[xr][kl];
                bf16x8 alx;
                if (xs) alx = *(const bf16x8*)&Xl[xr][kl];
                #pragma unroll
                for (int nt = 0; nt < 2; ++nt) {
                    const int wr = 32*ni + 16*nt + l16;
                    bf16x8 bh = *(const bf16x8*)&Wh[wr][kl];
                    acc[mt][nt] = MF(ahx, bh, acc[mt][nt]);
                    if (xs) acc[mt][nt] = MF(alx, bh, acc[mt][nt]);
                    if (ws) {
                        bf16x8 bl = *(const bf16x8*)&Wl[wr][kl];
                        acc[mt][nt] = MF(ahx, bl, acc[mt][nt]);
                    }
                }
            }
        }
    }
    unsigned short* vtH = nullptr;
    if (mode == 4) { vtH = (unsigned short*)(cur ? S0w : S1w); }
    #pragma unroll
    for (int nt = 0; nt < 2; ++nt) {
        const int col = n0 + 32*ni + 16*nt + l16;
        const float bv = bbf ? b2f(((const unsigned short*)Bv)[col]) : ((const float*)Bv)[col];
        #pragma unroll
        for (int mt = 0; mt < 2; ++mt)
            #pragma unroll
            for (int e = 0; e < 4; ++e) {
                const int row = m0 + 32*mi + 16*mt + quad*4 + e;
                const float vv = acc[mt][nt][e] + bv;
                const size_t idx = (size_t)row*HH + col;
                if (mode == 0) outF[idx] = vv;
                else if (mode == 1) {
                    if (obf) ((unsigned short*)outExt)[idx] = f2b(vv);
                    else     ((float*)outExt)[idx] = vv;
                } else {
                    unsigned short h, l; splitf(vv, h, l);
                    const size_t t = ((size_t)(row >> 11) * HH + col) * SS + (row & 2047);
                    if (mode == 3) {
                        pKH[idx] = h; pKL[idx] = l;
                        pKTH[t] = h;  pKTL[t] = l;
                    } else {                       // mode 4: V transposed planes
                        vtH[t] = h; vtH[(size_t)NN*HH + t] = l;
                    }
                }
            }
    }
}

// ---------- MFMA flash attention, split-bf16, 8 waves, counted-vmcnt DMA ----------
template<bool FINAL>
__global__ __launch_bounds__(512, 2) void mfma_attn(
    float* __restrict__ S0w, float* __restrict__ S1w,
    const unsigned short* __restrict__ KH, const unsigned short* __restrict__ KL,
    const unsigned short* __restrict__ KTH, const unsigned short* __restrict__ KTL,
    Ctl* sc)
{
    if constexpr (!FINAL) { if (sc->conv) return; }
    const int cur = sc->cur;
    float* Scur = cur ? S1w : S0w;
    float* Out  = FINAL ? Scur : (cur ? S0w : S1w);
    const unsigned short* VTH = FINAL ? (const unsigned short*)(cur ? S0w : S1w) : KTH;
    const unsigned short* VTL = FINAL ? (VTH + (size_t)NN*HH) : KTL;

    // 3 rotating unpadded DMA staging buffers (32KB each):
    // scores [2pl][64][128], PV [2pl][128][64]
    __shared__ __align__(16) unsigned short UB[3*16384];
    __shared__ __align__(16) unsigned short SHl[32*520];
    __shared__ __align__(16) unsigned short Pth[32*72], Ptl[32*72];
    __shared__ __align__(16) float Sld[32*68];
    __shared__ __align__(16) float mld[32], lld[32], ald[32];
    __shared__ float redd[8], redo[8];

    const int tid = threadIdx.x;
    const int lane = tid & 63, w = tid >> 6;          // w in 0..7
    const int quad = lane >> 4, l16 = lane & 15;
    const int r = w & 1, s = w >> 1;                  // r: 16-row half, s: 0..3

    const int bid = blockIdx.x;
    const int e8 = bid & 7;
    const int b = e8 >> 1;
    const int q0 = 32 * ((bid >> 3) + 32 * (e8 & 1));

    const size_t bSSHH = (size_t)b * SS * HH;
    const size_t bHHSS = (size_t)b * HH * SS;

    // ---- DMA staging helpers (4 calls/wave/phase, 16B/lane) ----
    // scores: LDS chunkidx = pl*1024 + j*512 + w*64 + lane
    //   -> key = 32j + 4w + quad, cpos = lane&15; src chunk' = cpos ^ (key&7)
    const int keyS = 4*w + quad;
    const int swS  = ((lane & 15) ^ (keyS & 7)) * 8;  // same for j=0,1 (32%8==0)
    // PV: LDS chunkidx = pl*1024 + j*512 + w*64 + lane
    //   -> row = 64j + 8w + (lane>>3), cpos = lane&7; src chunk' = cpos ^ (row&7)
    const int r3   = lane >> 3;
    const int swP  = ((lane & 7) ^ (r3 & 7)) * 8;
    const int rowP = 8*w + r3;                         // j=0 row; j=1 adds 64
    const int hidP0 = 128*(rowP >> 5) + (rowP & 31);   // + 32c
    const int hidP1 = 128*(2 + (rowP >> 5)) + (rowP & 31);

    auto stageS = [&](int c, int kt, unsigned short* ub) {
        const size_t g0 = bSSHH + (size_t)(kt*64 + keyS)*HH + c*128 + swS;
        const size_t g1 = bSSHH + (size_t)(kt*64 + keyS + 32)*HH + c*128 + swS;
        gl_lds16(KH + g0, ub +                 w*64*8);
        gl_lds16(KH + g1, ub +        4096 +   w*64*8);
        gl_lds16(KL + g0, ub + 8192 +          w*64*8);
        gl_lds16(KL + g1, ub + 8192 + 4096 +   w*64*8);
    };
    auto stageP = [&](int c, int kt, unsigned short* ub) {
        const size_t g0 = bHHSS + (size_t)(hidP0 + 32*c)*SS + (size_t)kt*64 + swP;
        const size_t g1 = bHHSS + (size_t)(hidP1 + 32*c)*SS + (size_t)kt*64 + swP;
        gl_lds16(VTH + g0, ub +                 w*64*8);
        gl_lds16(VTH + g1, ub +        4096 +   w*64*8);
        gl_lds16(VTL + g0, ub + 8192 +          w*64*8);
        gl_lds16(VTL + g1, ub + 8192 + 4096 +   w*64*8);
    };

    // ---- load state tile: hi frags to regs, lo plane to LDS (r10 scheme) ----
    bf16x8 ah[16];
    {
        const float* Qr = Scur + ((size_t)b*SS + q0 + 16*r + l16) * HH + quad*8;
        #pragma unroll
        for (int f = 0; f < 16; ++f) {
            float4 v0 = *(const float4*)(Qr + 32*f);
            float4 v1 = *(const float4*)(Qr + 32*f + 4);
            unsigned short h[8], l[8];
            splitf(v0.x,h[0],l[0]); splitf(v0.y,h[1],l[1]); splitf(v0.z,h[2],l[2]); splitf(v0.w,h[3],l[3]);
            splitf(v1.x,h[4],l[4]); splitf(v1.y,h[5],l[5]); splitf(v1.z,h[6],l[6]); splitf(v1.w,h[7],l[7]);
            bf16x8 af;
            #pragma unroll
            for (int j = 0; j < 8; ++j) af[j] = (short)h[j];
            ah[f] = af;
            if (s == 0) {
                unsigned short* d = &SHl[(16*r + l16)*520 + 32*f + quad*8];
                *(ushort4*)(d)     = make_ushort4(l[0], l[1], l[2], l[3]);
                *(ushort4*)(d + 4) = make_ushort4(l[4], l[5], l[6], l[7]);
            }
        }
        if (tid < 32) { mld[tid] = -INFINITY; lld[tid] = 0.f; }
    }

    // prologue DMAs AFTER the Q block (deterministic vmcnt counting):
    stageS(0, 0, UB);                 // phase 0 -> buf 0
    stageS(1, 0, UB + 16384);         // phase 1 -> buf 1

    f32x4 O[8];
    #pragma unroll
    for (int i = 0; i < 8; ++i) O[i] = (f32x4){0.f, 0.f, 0.f, 0.f};

    const int shlbase = (16*r + l16)*520 + quad*8;

    int cb = 0;                       // rotating buffer index of current phase
    for (int kt = 0; kt < SS/64; ++kt) {
        // 2 accumulator chains (even/odd kf) for MFMA-latency ILP
        f32x4 sA = (f32x4){0.f,0.f,0.f,0.f}, sB = (f32x4){0.f,0.f,0.f,0.f};
        // ---- scores: 4 phases of 128 hid; DMA issued TWO phases ahead ----
        #pragma unroll
        for (int c = 0; c < 4; ++c) {
            unsigned short* ub = UB + cb*16384;
            WBAR();                                    // this phase's DMA landed
            {
                int tb = cb + 2; if (tb >= 3) tb -= 3;
                unsigned short* tu = UB + tb*16384;
                if (c < 2) stageS(c+2, kt, tu);        // S2,S3
                else       stageP(c-2, kt, tu);        // P0,P1
            }
            #pragma unroll
            for (int kf = 0; kf < 4; ++kf) {
                bf16x8 alf = *(const bf16x8*)&SHl[shlbase + c*128 + kf*32];
                const int cc = ((4*kf + quad) ^ (l16 & 7)) * 8;
                bf16x8 bh = *(const bf16x8*)&ub[(16*s + l16)*128 + cc];
                bf16x8 bl = *(const bf16x8*)&ub[8192 + (16*s + l16)*128 + cc];
                const bf16x8 a = ah[c*4 + kf];
                if (kf & 1) {
                    sB = MF(a, bh, sB); sB = MF(alf, bh, sB); sB = MF(a, bl, sB);
                } else {
                    sA = MF(a, bh, sA); sA = MF(alf, bh, sA); sA = MF(a, bl, sA);
                }
            }
            cb = cb + 1; if (cb >= 3) cb = 0;
        }
        f32x4 sacc = sA + sB;
        #pragma unroll
        for (int e = 0; e < 4; ++e)
            Sld[(16*r + quad*4 + e)*68 + 16*s + l16] = sacc[e] * SCALE_F;
        FBAR();                                        // lgkm only: P0/P1 DMA stay in flight
        // ---- online softmax: 16 threads/row over 64 keys ----
        {
            const int row = tid >> 4, sg = tid & 15;
            const float* sr = Sld + row*68 + sg*4;
            float4 x0 = *(const float4*)(sr);
            float mt = fmaxf(fmaxf(x0.x, x0.y), fmaxf(x0.z, x0.w));
            #pragma unroll
            for (int mk = 1; mk < 16; mk <<= 1) mt = fmaxf(mt, __shfl_xor(mt, mk, 16));
            const float mprev = mld[row];
            const float mnew = fmaxf(mprev, mt);
            float p[4];
            p[0]=__expf(x0.x-mnew); p[1]=__expf(x0.y-mnew); p[2]=__expf(x0.z-mnew); p[3]=__expf(x0.w-mnew);
            float ps = p[0]+p[1]+p[2]+p[3];
            #pragma unroll
            for (int mk = 1; mk < 16; mk <<= 1) ps += __shfl_xor(ps, mk, 16);
            const float alpha = __expf(mprev - mnew);
            if (sg == 0) { mld[row] = mnew; lld[row] = lld[row]*alpha + ps; ald[row] = alpha; }
            unsigned short h[4], l[4];
            #pragma unroll
            for (int i = 0; i < 4; ++i) splitf(p[i], h[i], l[i]);
            *(ushort4*)&Pth[row*72 + sg*4] = make_ushort4(h[0],h[1],h[2],h[3]);
            *(ushort4*)&Ptl[row*72 + sg*4] = make_ushort4(l[0],l[1],l[2],l[3]);
        }
        FBAR();
        // ---- rescale O, load P frags ----
        {
            const float4 av = *(const float4*)&ald[16*r + 4*quad];
            const float a4[4] = {av.x, av.y, av.z, av.w};
            #pragma unroll
            for (int i = 0; i < 8; ++i)
                #pragma unroll
                for (int e = 0; e < 4; ++e) O[i][e] *= a4[e];
        }
        bf16x8 pah[2], pal[2];
        #pragma unroll
        for (int kf = 0; kf < 2; ++kf) {
            pah[kf] = *(const bf16x8*)&Pth[(16*r + l16)*72 + kf*32 + quad*8];
            pal[kf] = *(const bf16x8*)&Ptl[(16*r + l16)*72 + kf*32 + quad*8];
        }
        // ---- PV: 4 phases of 32-hid groups; DMA issued TWO phases ahead ----
        #pragma unroll
        for (int c = 0; c < 4; ++c) {
            unsigned short* ub = UB + cb*16384;
            WBAR();
            {
                int tb = cb + 2; if (tb >= 3) tb -= 3;
                unsigned short* tu = UB + tb*16384;
                if (c < 2) stageP(c+2, kt, tu);        // P2,P3
                else {
                    int ktn = kt + 1; if (ktn >= SS/64) ktn = 0;   // wrap: uniform count
                    stageS(c-2, ktn, tu);              // S0,S1 of next kt
                }
            }
            #pragma unroll
            for (int nt = 0; nt < 2; ++nt) {
                const int rb = (32*s + 16*nt + l16)*64;
                #pragma unroll
                for (int kf = 0; kf < 2; ++kf) {
                    const int cc = ((4*kf + quad) ^ (l16 & 7)) * 8;
                    bf16x8 bh = *(const bf16x8*)&ub[rb + cc];
                    bf16x8 bl = *(const bf16x8*)&ub[8192 + rb + cc];
                    O[c*2+nt] = MF(pah[kf], bh, O[c*2+nt]);
                    O[c*2+nt] = MF(pal[kf], bh, O[c*2+nt]);
                    O[c*2+nt] = MF(pah[kf], bl, O[c*2+nt]);
                }
            }
            cb = cb + 1; if (cb >= 3) cb = 0;
        }
    }
    // ---- epilogue ----
    const float4 lv = *(const float4*)&lld[16*r + 4*quad];
    const float inv[4] = {1.f/lv.x, 1.f/lv.y, 1.f/lv.z, 1.f/lv.w};
    float pd = 0.f, po2 = 0.f;
    #pragma unroll
    for (int c = 0; c < 4; ++c)
        #pragma unroll
        for (int nt = 0; nt < 2; ++nt)
            #pragma unroll
            for (int e = 0; e < 4; ++e) {
                const int row = q0 + 16*r + quad*4 + e;
                const int col = 128*s + 32*c + 16*nt + l16;
                const float nv = O[c*2+nt][e] * inv[e];
                const size_t idx = (size_t)b*SS*HH + (size_t)row*HH + col;
                if constexpr (!FINAL) {
                    const float old = Scur[idx];
                    const float d = nv - old;
                    pd += d*d; po2 += old*old;
                }
                Out[idx] = nv;
            }
    if constexpr (!FINAL) {
        #pragma unroll
        for (int mk = 1; mk < 64; mk <<= 1) {
            pd  += __shfl_xor(pd, mk, 64);
            po2 += __shfl_xor(po2, mk, 64);
        }
        if (lane == 0) { redd[w] = pd; redo[w] = po2; }
        __syncthreads();
        if (tid == 0) {
            float td = 0.f, to = 0.f;
            #pragma unroll
            for (int i = 0; i < 8; ++i) { td += redd[i]; to += redo[i]; }
            atomicAdd(&sc->sum_d, td);
            atomicAdd(&sc->sum_o, to);
        }
    }
}

__global__ __launch_bounds__(64) void flag_update(Ctl* sc) {
    if (threadIdx.x != 0) return;
    if (sc->conv) return;
    sc->cur ^= 1;
    sc->iters += 1;
    const float delta = sqrtf(sc->sum_d) / (sqrtf(sc->sum_o) + 1e-8f);
    if (delta < THRESH) sc->conv = 1;
    sc->sum_d = 0.f; sc->sum_o = 0.f;
}

__global__ __launch_bounds__(64) void write_scalars(const Ctl* sc, void* outv) {
    if (threadIdx.x != 0) return;
    if (sc->bf[9]) {
        unsigned short* o = (unsigned short*)outv;
        o[(size_t)NN*HH]     = f2b((float)sc->iters);
        o[(size_t)NN*HH + 1] = f2b(sc->conv ? 1.0f : 0.0f);
    } else {
        float* o = (float*)outv;
        o[(size_t)NN*HH]     = (float)sc->iters;
        o[(size_t)NN*HH + 1] = sc->conv ? 1.0f : 0.0f;
    }
}

extern "C" void kernel_launch(void* const* d_in, const int* in_sizes, int n_in,
                              void* d_out, int out_size, void* d_ws, size_t ws_size,
                              hipStream_t stream)
{
    const void* x  = d_in[0];
    const void* Wq = d_in[1];
    const void* bq = d_in[2];
    const void* Wk = d_in[3];
    const void* bk = d_in[4];
    const void* Wv = d_in[5];
    const void* bv = d_in[6];
    const void* Wo = d_in[7];
    const void* bo = d_in[8];

    Ctl* sc = (Ctl*)d_ws;
    float* S0 = (float*)d_ws + CTL_FLOATS;                 // [NN,HH] fp32 state ping
    float* S1 = S0 + (size_t)NN*HH;                        // [NN,HH] fp32 state pong / VT planes
    unsigned short* KH  = (unsigned short*)(S1 + (size_t)NN*HH);
    unsigned short* KL  = KH  + (size_t)NN*HH;
    unsigned short* KTH = KL  + (size_t)NN*HH;
    unsigned short* KTL = KTH + (size_t)NN*HH;             // total ~67.1 MB (proven)

    const dim3 ggrid(NN/64, HH/64);   // 128 x 8
    const int  agrid = 256;           // 1D, XCD-swizzled

    detect_dtypes<<<9, 256, 0, stream>>>(x, Wq, bq, Wk, bk, Wv, bv, Wo, bo, sc);
    init_flags<<<1, 64, 0, stream>>>(sc);

    // Q projection -> S0 (fp32)
    mfma_gemm<<<ggrid, 256, 0, stream>>>(x, 0, Wq, 1, bq, 2, S0, nullptr,
                                         nullptr, nullptr, nullptr, nullptr, S0, S1, 0, sc);
    // K projection -> KH/KL + transposed KTH/KTL
    mfma_gemm<<<ggrid, 256, 0, stream>>>(x, 0, Wk, 3, bk, 4, nullptr, nullptr,
                                         KH, KL, KTH, KTL, S0, S1, 3, sc);

    for (int it = 0; it < 5; ++it) {
        mfma_attn<false><<<agrid, 512, 0, stream>>>(S0, S1, KH, KL, KTH, KTL, sc);
        flag_update<<<1, 64, 0, stream>>>(sc);
    }

    // V projection -> transposed planes into the dead state buffer buf[1^cur]
    mfma_gemm<<<ggrid, 256, 0, stream>>>(x, 0, Wv, 5, bv, 6, nullptr, nullptr,
                                         nullptr, nullptr, nullptr, nullptr, S0, S1, 4, sc);
    // Final readout attention (in-place on buf[cur], V from VT planes)
    mfma_attn<true><<<agrid, 512, 0, stream>>>(S0, S1, KH, KL, KTH, KTL, sc);
    // Output projection from buf[cur]
    mfma_gemm<<<ggrid, 256, 0, stream>>>(nullptr, -2, Wo, 7, bo, 8, nullptr, d_out,
                                         nullptr, nullptr, nullptr, nullptr, S0, S1, 1, sc);
    if (out_size >= (int)((size_t)NN*HH + 2))
        write_scalars<<<1, 64, 0, stream>>>(sc, d_out);
}

// Round 9
// 1290.235 us; speedup vs baseline: 1.4576x; 1.4576x over previous
//
#include <hip/hip_runtime.h>
#include <hip/hip_bf16.h>
#include <math.h>

// TrueHopfieldLayer: HIDDEN=512, B=4, S=2048, 5 iters, thresh 1e-4.
// Round 15: exact r10 (champion: attn 218us, total 1277us) + XOR bank-swizzle
// on the staging buffers (the one transplantable win from the DMA detour:
// r13 proved the swizzle halves conflicts). DMA/global_load_lds path is
// ABANDONED: compiler inserts vmcnt(0) before dependent ds_reads, defeating
// counted waits (r13 245us, r14 293us vs r10's 218).
// Changes vs r10 (values bit-identical, placement permuted per-row):
//  - staging buffers unpadded: scores [64][128], PV [128][64], 32KB each.
//  - ring ST4 writes each 16B uint4 to granule g^(row&7) (per-store addr).
//  - MFMA B-reads at granule (4kf+quad)^(l16&7) (rows 16s+l16 / 32s+16nt+l16
//    are all == l16 mod 8).
//  - global fetch addresses unchanged; reads/writes use the same involution.
// Everything else byte-identical to r10: distance-2 Ra/Rb ring, FBAR
// lgkm-only, 4+4 phases, softmax, epilogue, __launch_bounds__(512,2).
#define HH 512
#define BB 4
#define SS 2048
#define NN (BB*SS)
#define SCALE_F 0.04419417382415922f     // 1/sqrt(512)
#define THRESH 1e-4f
#define CTL_FLOATS 1024

typedef __attribute__((ext_vector_type(8))) short bf16x8;
typedef __attribute__((ext_vector_type(4))) float f32x4;

struct Ctl { float sum_d; float sum_o; int iters; int conv; int cur; int bf[10]; };

__device__ __forceinline__ float b2f(unsigned short u) {
    union { unsigned int i; float f; } c; c.i = ((unsigned int)u) << 16; return c.f;
}
__device__ __forceinline__ unsigned short f2b(float f) {
    unsigned int x = __float_as_uint(f);
    unsigned int r = (x + 0x7FFFu + ((x >> 16) & 1u)) >> 16;   // RNE
    return (unsigned short)r;
}
__device__ __forceinline__ void splitf(float x, unsigned short& h, unsigned short& l) {
    h = f2b(x);
    l = f2b(x - b2f(h));
}
__device__ __forceinline__ f32x4 MF(bf16x8 a, bf16x8 b, f32x4 c) {
    return __builtin_amdgcn_mfma_f32_16x16x32_bf16(a, b, c, 0, 0, 0);
}

// barrier that drains only LDS ops; prefetched global loads stay in flight
#define FBAR() do { \
    asm volatile("s_waitcnt lgkmcnt(0)" ::: "memory"); \
    __builtin_amdgcn_s_barrier(); \
    asm volatile("" ::: "memory"); \
} while (0)

// Prefetch ring load (R = Ra or Rb): 16 ush hi (R0,R1) + 16 ush lo (R2,R3).
#define LD4(R, ph, pl) do { \
    const unsigned short* _ph = (ph); const unsigned short* _pl = (pl); \
    R##0 = *(const uint4*)(_ph); R##1 = *(const uint4*)(_ph + 8); \
    R##2 = *(const uint4*)(_pl); R##3 = *(const uint4*)(_pl + 8); \
} while (0)
// Swizzled store: base = row start (hi plane), row = LDS row, g0 = first
// 8-ush granule. Each 16B store gets its own XOR'd granule address.
// Lo plane at +8192 ush.
#define ST4SW(base, rowv, g0v, R) do { \
    unsigned short* _b = (base); \
    const int _r7 = (rowv) & 7; \
    unsigned short* _d0 = _b + ((((g0v))     ^ _r7) << 3); \
    unsigned short* _d1 = _b + ((((g0v) + 1) ^ _r7) << 3); \
    *(uint4*)_d0 = R##0; *(uint4*)_d1 = R##1; \
    *(uint4*)(_d0 + 8192) = R##2; *(uint4*)(_d1 + 8192) = R##3; \
} while (0)

// ---------- dtype detection (proven) ----------
__global__ __launch_bounds__(256) void detect_dtypes(
        const void* p0, const void* p1, const void* p2, const void* p3, const void* p4,
        const void* p5, const void* p6, const void* p7, const void* p8, Ctl* sc)
{
    const void* ps[9] = {p0,p1,p2,p3,p4,p5,p6,p7,p8};
    const int   ns[9] = {NN*HH, HH*HH, HH, HH*HH, HH, HH*HH, HH, HH*HH, HH};
    const int i = blockIdx.x;
    const unsigned short* u = (const unsigned short*)ps[i];
    const int n = ns[i] < 4096 ? ns[i] : 4096;
    __shared__ int cnt;
    if (threadIdx.x == 0) cnt = 0;
    __syncthreads();
    int c = 0;
    for (int j = threadIdx.x; j < n; j += 256) {
        const int e = (u[j] >> 7) & 0xFF;
        if (e < 32 || e >= 224) ++c;
    }
    if (c) atomicAdd(&cnt, c);
    __syncthreads();
    if (threadIdx.x == 0) sc->bf[i] = (cnt * 16 < n) ? 1 : 0;
}

__global__ __launch_bounds__(64) void init_flags(Ctl* sc) {
    if (threadIdx.x == 0) {
        sc->iters = 0; sc->conv = 0; sc->cur = 0; sc->sum_d = 0.f; sc->sum_o = 0.f;
        int any = 0;
        for (int i = 0; i < 9; ++i) any |= sc->bf[i];
        sc->bf[9] = any;
    }
}

// ---------- MFMA GEMM: C = X @ W^T + bias ----------
// mode 0: fp32 out (Q->state). mode 1: external out (X = state[cur] fp32 when xIdx==-2).
// mode 3: K -> KH,KL row-major + KTH,KTL transposed ([b][h][s]) planes.
// mode 4: V -> transposed planes into dead state buffer buf[1^cur].
__global__ __launch_bounds__(256) void mfma_gemm(
    const void* __restrict__ Xv, int xIdx,
    const void* __restrict__ Wv, int wIdx,
    const void* __restrict__ Bv, int bIdx,
    float* __restrict__ outF, void* __restrict__ outExt,
    unsigned short* __restrict__ pKH, unsigned short* __restrict__ pKL,
    unsigned short* __restrict__ pKTH, unsigned short* __restrict__ pKTL,
    float* __restrict__ S0w, float* __restrict__ S1w,
    int mode, const Ctl* __restrict__ sc)
{
    __shared__ unsigned short Xh[64][72], Xl[64][72], Wh[64][72], Wl[64][72];
    const int tid = threadIdx.x;
    const int cur = sc->cur;
    const void* Xp = (xIdx == -2) ? (const void*)(cur ? S1w : S0w) : Xv;
    const bool xbf = (xIdx >= 0) && (sc->bf[xIdx] != 0);
    const bool wbf = (sc->bf[wIdx] != 0);
    const bool bbf = (sc->bf[bIdx] != 0);
    const bool obf = (mode == 1) && (sc->bf[9] != 0);
    const bool xs = !xbf, ws = !wbf;

    const int m0 = blockIdx.x * 64, n0 = blockIdx.y * 64;
    const int lane = tid & 63, w = tid >> 6;
    const int mi = w & 1, ni = w >> 1;
    const int quad = lane >> 4, l16 = lane & 15;
    const int srow = tid >> 2, skb = (tid & 3) * 16;

    f32x4 acc[2][2];
    #pragma unroll
    for (int a = 0; a < 2; ++a)
        #pragma unroll
        for (int bq = 0; bq < 2; ++bq) acc[a][bq] = (f32x4){0.f, 0.f, 0.f, 0.f};

    for (int kc = 0; kc < HH; kc += 64) {
        __syncthreads();
        {
            float v[16];
            if (xbf) {
                const unsigned short* p = (const unsigned short*)Xp + (size_t)(m0 + srow)*HH + kc + skb;
                #pragma unroll
                for (int i = 0; i < 4; ++i) {
                    ushort4 t = *(const ushort4*)(p + 4*i);
                    v[4*i]=b2f(t.x); v[4*i+1]=b2f(t.y); v[4*i+2]=b2f(t.z); v[4*i+3]=b2f(t.w);
                }
            } else {
                const float* p = (const float*)Xp + (size_t)(m0 + srow)*HH + kc + skb;
                #pragma unroll
                for (int i = 0; i < 4; ++i) {
                    float4 t = *(const float4*)(p + 4*i);
                    v[4*i]=t.x; v[4*i+1]=t.y; v[4*i+2]=t.z; v[4*i+3]=t.w;
                }
            }
            #pragma unroll
            for (int i = 0; i < 4; ++i) {
                unsigned short h[4], l[4];
                #pragma unroll
                for (int j = 0; j < 4; ++j) splitf(v[4*i+j], h[j], l[j]);
                *(ushort4*)&Xh[srow][skb + 4*i] = make_ushort4(h[0], h[1], h[2], h[3]);
                if (xs) *(ushort4*)&Xl[srow][skb + 4*i] = make_ushort4(l[0], l[1], l[2], l[3]);
            }
        }
        {
            float v[16];
            if (wbf) {
                const unsigned short* p = (const unsigned short*)Wv + (size_t)(n0 + srow)*HH + kc + skb;
                #pragma unroll
                for (int i = 0; i < 4; ++i) {
                    ushort4 t = *(const ushort4*)(p + 4*i);
                    v[4*i]=b2f(t.x); v[4*i+1]=b2f(t.y); v[4*i+2]=b2f(t.z); v[4*i+3]=b2f(t.w);
                }
            } else {
                const float* p = (const float*)Wv + (size_t)(n0 + srow)*HH + kc + skb;
                #pragma unroll
                for (int i = 0; i < 4; ++i) {
                    float4 t = *(const float4*)(p + 4*i);
                    v[4*i]=t.x; v[4*i+1]=t.y; v[4*i+2]=t.z; v[4*i+3]=t.w;
                }
            }
            #pragma unroll
            for (int i = 0; i < 4; ++i) {
                unsigned short h[4], l[4];
                #pragma unroll
                for (int j = 0; j < 4; ++j) splitf(v[4*i+j], h[j], l[j]);
                *(ushort4*)&Wh[srow][skb + 4*i] = make_ushort4(h[0], h[1], h[2], h[3]);
                if (ws) *(ushort4*)&Wl[srow][skb + 4*i] = make_ushort4(l[0], l[1], l[2], l[3]);
            }
        }
        __syncthreads();
        #pragma unroll
        for (int d = 0; d < 2; ++d) {
            const int kl = 32*d + quad*8;
            #pragma unroll
            for (int mt = 0; mt < 2; ++mt) {
                const int xr = 32*mi + 16*mt + l16;
                bf16x8 ahx = *(const bf16x8*)&Xh[xr][kl];
                bf16x8 alx;
                if (xs) alx = *(const bf16x8*)&Xl[xr][kl];
                #pragma unroll
                for (int nt = 0; nt < 2; ++nt) {
                    const int wr = 32*ni + 16*nt + l16;
                    bf16x8 bh = *(const bf16x8*)&Wh[wr][kl];
                    acc[mt][nt] = MF(ahx, bh, acc[mt][nt]);
                    if (xs) acc[mt][nt] = MF(alx, bh, acc[mt][nt]);
                    if (ws) {
                        bf16x8 bl = *(const bf16x8*)&Wl[wr][kl];
                        acc[mt][nt] = MF(ahx, bl, acc[mt][nt]);
                    }
                }
            }
        }
    }
    unsigned short* vtH = nullptr;
    if (mode == 4) { vtH = (unsigned short*)(cur ? S0w : S1w); }
    #pragma unroll
    for (int nt = 0; nt < 2; ++nt) {
        const int col = n0 + 32*ni + 16*nt + l16;
        const float bv = bbf ? b2f(((const unsigned short*)Bv)[col]) : ((const float*)Bv)[col];
        #pragma unroll
        for (int mt = 0; mt < 2; ++mt)
            #pragma unroll
            for (int e = 0; e < 4; ++e) {
                const int row = m0 + 32*mi + 16*mt + quad*4 + e;
                const float vv = acc[mt][nt][e] + bv;
                const size_t idx = (size_t)row*HH + col;
                if (mode == 0) outF[idx] = vv;
                else if (mode == 1) {
                    if (obf) ((unsigned short*)outExt)[idx] = f2b(vv);
                    else     ((float*)outExt)[idx] = vv;
                } else {
                    unsigned short h, l; splitf(vv, h, l);
                    const size_t t = ((size_t)(row >> 11) * HH + col) * SS + (row & 2047);
                    if (mode == 3) {
                        pKH[idx] = h; pKL[idx] = l;
                        pKTH[t] = h;  pKTL[t] = l;
                    } else {                       // mode 4: V transposed planes
                        vtH[t] = h; vtH[(size_t)NN*HH + t] = l;
                    }
                }
            }
    }
}

// ---------- MFMA flash attention, split-bf16, 8 waves, swizzled staging ----------
template<bool FINAL>
__global__ __launch_bounds__(512, 2) void mfma_attn(
    float* __restrict__ S0w, float* __restrict__ S1w,
    const unsigned short* __restrict__ KH, const unsigned short* __restrict__ KL,
    const unsigned short* __restrict__ KTH, const unsigned short* __restrict__ KTL,
    Ctl* sc)
{
    if constexpr (!FINAL) { if (sc->conv) return; }
    const int cur = sc->cur;
    float* Scur = cur ? S1w : S0w;
    float* Out  = FINAL ? Scur : (cur ? S0w : S1w);
    const unsigned short* VTH = FINAL ? (const unsigned short*)(cur ? S0w : S1w) : KTH;
    const unsigned short* VTL = FINAL ? (VTH + (size_t)NN*HH) : KTL;

    // unpadded swizzled staging: scores [64][128] hi + lo, PV [128][64] hi + lo
    __shared__ __align__(16) unsigned short UB0[16384];
    __shared__ __align__(16) unsigned short UB1[16384];
    __shared__ __align__(16) unsigned short SHl[32*520];
    __shared__ __align__(16) unsigned short Pth[32*72], Ptl[32*72];
    __shared__ __align__(16) float Sld[32*68];
    __shared__ __align__(16) float mld[32], lld[32], ald[32];
    __shared__ float redd[8], redo[8];

    const int tid = threadIdx.x;
    const int lane = tid & 63, w = tid >> 6;          // w in 0..7
    const int quad = lane >> 4, l16 = lane & 15;
    const int r = w & 1, s = w >> 1;                  // r: 16-row half, s: 0..3

    const int bid = blockIdx.x;
    const int e8 = bid & 7;
    const int b = e8 >> 1;
    const int q0 = 32 * ((bid >> 3) + 32 * (e8 & 1));

    const size_t bSSHH = (size_t)b * SS * HH;
    const size_t bHHSS = (size_t)b * HH * SS;

    const int key = tid >> 3, hs = (tid & 7) * 16;    // scores staging: 64 rows x 8x16
    const int gS  = (tid & 7) * 2;                    // first granule (8-ush) of this strip
    const int rw = tid >> 2, k1 = (tid & 3) * 16;     // PV staging: 128 rows x 4x16
    const int gP  = (tid & 3) * 2;

    const unsigned short* pSH = KH + bSSHH + (size_t)key*HH + hs;
    const unsigned short* pSL = KL + bSSHH + (size_t)key*HH + hs;
    // PV chunk c stages hid rows 128*(rw>>5) + 32*c + (rw&31)
    const size_t vbase = bHHSS + (size_t)(128*(rw >> 5) + (rw & 31))*SS + k1;
    const unsigned short* pVH = VTH + vbase;
    const unsigned short* pVL = VTL + vbase;

    // 2-deep prefetch ring: 8 NAMED uint4 registers
    uint4 Ra0, Ra1, Ra2, Ra3;
    uint4 Rb0, Rb1, Rb2, Rb3;
    LD4(Ra, pSH, pSL);              // S(kt=0, c=0)
    LD4(Rb, pSH + 128, pSL + 128);  // S(kt=0, c=1)

    // ---- load state tile: hi frags to regs, lo plane to LDS ----
    bf16x8 ah[16];
    {
        const float* Qr = Scur + ((size_t)b*SS + q0 + 16*r + l16) * HH + quad*8;
        #pragma unroll
        for (int f = 0; f < 16; ++f) {
            float4 v0 = *(const float4*)(Qr + 32*f);
            float4 v1 = *(const float4*)(Qr + 32*f + 4);
            unsigned short h[8], l[8];
            splitf(v0.x,h[0],l[0]); splitf(v0.y,h[1],l[1]); splitf(v0.z,h[2],l[2]); splitf(v0.w,h[3],l[3]);
            splitf(v1.x,h[4],l[4]); splitf(v1.y,h[5],l[5]); splitf(v1.z,h[6],l[6]); splitf(v1.w,h[7],l[7]);
            bf16x8 af;
            #pragma unroll
            for (int j = 0; j < 8; ++j) af[j] = (short)h[j];
            ah[f] = af;
            if (s == 0) {
                unsigned short* d = &SHl[(16*r + l16)*520 + 32*f + quad*8];
                *(ushort4*)(d)     = make_ushort4(l[0], l[1], l[2], l[3]);
                *(ushort4*)(d + 4) = make_ushort4(l[4], l[5], l[6], l[7]);
            }
        }
        if (tid < 32) { mld[tid] = -INFINITY; lld[tid] = 0.f; }
    }

    f32x4 O[8];
    #pragma unroll
    for (int i = 0; i < 8; ++i) O[i] = (f32x4){0.f, 0.f, 0.f, 0.f};

    const int shlbase = (16*r + l16)*520 + quad*8;
    const int gsw = l16 & 7;                          // read-side swizzle key

    for (int kt = 0; kt < SS/64; ++kt) {
        const size_t so = (size_t)kt*64*HH;               // scores row offset
        const size_t po = (size_t)kt*64;                  // PV col offset
        // 2 accumulator chains (even/odd kf) for MFMA-latency ILP
        f32x4 sA = (f32x4){0.f,0.f,0.f,0.f}, sB = (f32x4){0.f,0.f,0.f,0.f};
        // ---- scores: 4 hid-chunks of 128, dbuf + prefetch(+2) ----
        #pragma unroll
        for (int c = 0; c < 4; ++c) {
            unsigned short* ub = (c & 1) ? UB1 : UB0;     // compile-time select
            if ((c & 1) == 0) {
                ST4SW(ub + key*128, key, gS, Ra);
                if (c == 0) LD4(Ra, pSH + so + 2*128, pSL + so + 2*128);
                else        LD4(Ra, pVH + po, pVL + po);                      // c==2: PV chunk 0
            } else {
                ST4SW(ub + key*128, key, gS, Rb);
                if (c == 1) LD4(Rb, pSH + so + 3*128, pSL + so + 3*128);
                else        LD4(Rb, pVH + (size_t)32*SS + po, pVL + (size_t)32*SS + po);  // c==3: PV chunk 1
            }
            FBAR();
            #pragma unroll
            for (int kf = 0; kf < 4; ++kf) {
                bf16x8 alf = *(const bf16x8*)&SHl[shlbase + c*128 + kf*32];
                const int cc = ((4*kf + quad) ^ gsw) << 3;
                const int rb = (16*s + l16)*128;
                bf16x8 bh = *(const bf16x8*)&ub[rb + cc];
                bf16x8 bl = *(const bf16x8*)&ub[8192 + rb + cc];
                const bf16x8 a = ah[c*4 + kf];
                if (kf & 1) {
                    sB = MF(a, bh, sB); sB = MF(alf, bh, sB); sB = MF(a, bl, sB);
                } else {
                    sA = MF(a, bh, sA); sA = MF(alf, bh, sA); sA = MF(a, bl, sA);
                }
            }
        }
        f32x4 sacc = sA + sB;
        #pragma unroll
        for (int e = 0; e < 4; ++e)
            Sld[(16*r + quad*4 + e)*68 + 16*s + l16] = sacc[e] * SCALE_F;
        FBAR();
        // ---- online softmax: 16 threads/row over 64 keys ----
        {
            const int row = tid >> 4, sg = tid & 15;
            const float* sr = Sld + row*68 + sg*4;
            float4 x0 = *(const float4*)(sr);
            float mt = fmaxf(fmaxf(x0.x, x0.y), fmaxf(x0.z, x0.w));
            #pragma unroll
            for (int mk = 1; mk < 16; mk <<= 1) mt = fmaxf(mt, __shfl_xor(mt, mk, 16));
            const float mprev = mld[row];
            const float mnew = fmaxf(mprev, mt);
            float p[4];
            p[0]=__expf(x0.x-mnew); p[1]=__expf(x0.y-mnew); p[2]=__expf(x0.z-mnew); p[3]=__expf(x0.w-mnew);
            float ps = p[0]+p[1]+p[2]+p[3];
            #pragma unroll
            for (int mk = 1; mk < 16; mk <<= 1) ps += __shfl_xor(ps, mk, 16);
            const float alpha = __expf(mprev - mnew);
            if (sg == 0) { mld[row] = mnew; lld[row] = lld[row]*alpha + ps; ald[row] = alpha; }
            unsigned short h[4], l[4];
            #pragma unroll
            for (int i = 0; i < 4; ++i) splitf(p[i], h[i], l[i]);
            *(ushort4*)&Pth[row*72 + sg*4] = make_ushort4(h[0],h[1],h[2],h[3]);
            *(ushort4*)&Ptl[row*72 + sg*4] = make_ushort4(l[0],l[1],l[2],l[3]);
        }
        FBAR();
        // ---- rescale O, load P frags ----
        {
            const float4 av = *(const float4*)&ald[16*r + 4*quad];
            const float a4[4] = {av.x, av.y, av.z, av.w};
            #pragma unroll
            for (int i = 0; i < 8; ++i)
                #pragma unroll
                for (int e = 0; e < 4; ++e) O[i][e] *= a4[e];
        }
        bf16x8 pah[2], pal[2];
        #pragma unroll
        for (int kf = 0; kf < 2; ++kf) {
            pah[kf] = *(const bf16x8*)&Pth[(16*r + l16)*72 + kf*32 + quad*8];
            pal[kf] = *(const bf16x8*)&Ptl[(16*r + l16)*72 + kf*32 + quad*8];
        }
        // ---- PV: 4 chunks of 32 hid-cols/warp, dbuf + prefetch(+2) ----
        #pragma unroll
        for (int c = 0; c < 4; ++c) {
            unsigned short* ub = (c & 1) ? UB1 : UB0;     // compile-time select
            if ((c & 1) == 0) {
                ST4SW(ub + rw*64, rw, gP, Ra);
                if (c == 0)             LD4(Ra, pVH + (size_t)64*SS + po, pVL + (size_t)64*SS + po);
                else if (kt+1 < SS/64)  LD4(Ra, pSH + so + (size_t)64*HH,
                                             pSL + so + (size_t)64*HH);       // next-kt S chunk 0
            } else {
                ST4SW(ub + rw*64, rw, gP, Rb);
                if (c == 1)             LD4(Rb, pVH + (size_t)96*SS + po, pVL + (size_t)96*SS + po);
                else if (kt+1 < SS/64)  LD4(Rb, pSH + so + (size_t)64*HH + 128,
                                             pSL + so + (size_t)64*HH + 128); // next-kt S chunk 1
            }
            FBAR();
            #pragma unroll
            for (int nt = 0; nt < 2; ++nt) {
                const int rb = (32*s + 16*nt + l16)*64;
                #pragma unroll
                for (int kf = 0; kf < 2; ++kf) {
                    const int cc = ((4*kf + quad) ^ gsw) << 3;
                    bf16x8 bh = *(const bf16x8*)&ub[rb + cc];
                    bf16x8 bl = *(const bf16x8*)&ub[8192 + rb + cc];
                    O[c*2+nt] = MF(pah[kf], bh, O[c*2+nt]);
                    O[c*2+nt] = MF(pal[kf], bh, O[c*2+nt]);
                    O[c*2+nt] = MF(pah[kf], bl, O[c*2+nt]);
                }
            }
        }
    }
    // ---- epilogue ----
    const float4 lv = *(const float4*)&lld[16*r + 4*quad];
    const float inv[4] = {1.f/lv.x, 1.f/lv.y, 1.f/lv.z, 1.f/lv.w};
    float pd = 0.f, po2 = 0.f;
    #pragma unroll
    for (int c = 0; c < 4; ++c)
        #pragma unroll
        for (int nt = 0; nt < 2; ++nt)
            #pragma unroll
            for (int e = 0; e < 4; ++e) {
                const int row = q0 + 16*r + quad*4 + e;
                const int col = 128*s + 32*c + 16*nt + l16;
                const float nv = O[c*2+nt][e] * inv[e];
                const size_t idx = (size_t)b*SS*HH + (size_t)row*HH + col;
                if constexpr (!FINAL) {
                    const float old = Scur[idx];
                    const float d = nv - old;
                    pd += d*d; po2 += old*old;
                }
                Out[idx] = nv;
            }
    if constexpr (!FINAL) {
        #pragma unroll
        for (int mk = 1; mk < 64; mk <<= 1) {
            pd  += __shfl_xor(pd, mk, 64);
            po2 += __shfl_xor(po2, mk, 64);
        }
        if (lane == 0) { redd[w] = pd; redo[w] = po2; }
        __syncthreads();
        if (tid == 0) {
            float td = 0.f, to = 0.f;
            #pragma unroll
            for (int i = 0; i < 8; ++i) { td += redd[i]; to += redo[i]; }
            atomicAdd(&sc->sum_d, td);
            atomicAdd(&sc->sum_o, to);
        }
    }
}

__global__ __launch_bounds__(64) void flag_update(Ctl* sc) {
    if (threadIdx.x != 0) return;
    if (sc->conv) return;
    sc->cur ^= 1;
    sc->iters += 1;
    const float delta = sqrtf(sc->sum_d) / (sqrtf(sc->sum_o) + 1e-8f);
    if (delta < THRESH) sc->conv = 1;
    sc->sum_d = 0.f; sc->sum_o = 0.f;
}

__global__ __launch_bounds__(64) void write_scalars(const Ctl* sc, void* outv) {
    if (threadIdx.x != 0) return;
    if (sc->bf[9]) {
        unsigned short* o = (unsigned short*)outv;
        o[(size_t)NN*HH]     = f2b((float)sc->iters);
        o[(size_t)NN*HH + 1] = f2b(sc->conv ? 1.0f : 0.0f);
    } else {
        float* o = (float*)outv;
        o[(size_t)NN*HH]     = (float)sc->iters;
        o[(size_t)NN*HH + 1] = sc->conv ? 1.0f : 0.0f;
    }
}

extern "C" void kernel_launch(void* const* d_in, const int* in_sizes, int n_in,
                              void* d_out, int out_size, void* d_ws, size_t ws_size,
                              hipStream_t stream)
{
    const void* x  = d_in[0];
    const void* Wq = d_in[1];
    const void* bq = d_in[2];
    const void* Wk = d_in[3];
    const void* bk = d_in[4];
    const void* Wv = d_in[5];
    const void* bv = d_in[6];
    const void* Wo = d_in[7];
    const void* bo = d_in[8];

    Ctl* sc = (Ctl*)d_ws;
    float* S0 = (float*)d_ws + CTL_FLOATS;                 // [NN,HH] fp32 state ping
    float* S1 = S0 + (size_t)NN*HH;                        // [NN,HH] fp32 state pong / VT planes
    unsigned short* KH  = (unsigned short*)(S1 + (size_t)NN*HH);
    unsigned short* KL  = KH  + (size_t)NN*HH;
    unsigned short* KTH = KL  + (size_t)NN*HH;
    unsigned short* KTL = KTH + (size_t)NN*HH;             // total ~67.1 MB (proven)

    const dim3 ggrid(NN/64, HH/64);   // 128 x 8
    const int  agrid = 256;           // 1D, XCD-swizzled

    detect_dtypes<<<9, 256, 0, stream>>>(x, Wq, bq, Wk, bk, Wv, bv, Wo, bo, sc);
    init_flags<<<1, 64, 0, stream>>>(sc);

    // Q projection -> S0 (fp32)
    mfma_gemm<<<ggrid, 256, 0, stream>>>(x, 0, Wq, 1, bq, 2, S0, nullptr,
                                         nullptr, nullptr, nullptr, nullptr, S0, S1, 0, sc);
    // K projection -> KH/KL + transposed KTH/KTL
    mfma_gemm<<<ggrid, 256, 0, stream>>>(x, 0, Wk, 3, bk, 4, nullptr, nullptr,
                                         KH, KL, KTH, KTL, S0, S1, 3, sc);

    for (int it = 0; it < 5; ++it) {
        mfma_attn<false><<<agrid, 512, 0, stream>>>(S0, S1, KH, KL, KTH, KTL, sc);
        flag_update<<<1, 64, 0, stream>>>(sc);
    }

    // V projection -> transposed planes into the dead state buffer buf[1^cur]
    mfma_gemm<<<ggrid, 256, 0, stream>>>(x, 0, Wv, 5, bv, 6, nullptr, nullptr,
                                         nullptr, nullptr, nullptr, nullptr, S0, S1, 4, sc);
    // Final readout attention (in-place on buf[cur], V from VT planes)
    mfma_attn<true><<<agrid, 512, 0, stream>>>(S0, S1, KH, KL, KTH, KTL, sc);
    // Output projection from buf[cur]
    mfma_gemm<<<ggrid, 256, 0, stream>>>(nullptr, -2, Wo, 7, bo, 8, nullptr, d_out,
                                         nullptr, nullptr, nullptr, nullptr, S0, S1, 1, sc);
    if (out_size >= (int)((size_t)NN*HH + 2))
        write_scalars<<<1, 64, 0, stream>>>(sc, d_out);
}